// Round 1
// baseline (292.957 us; speedup 1.0000x reference)
//
#include <hip/hip_runtime.h>

#define N 4096
#define NB 32  // N / 128

typedef __bf16 bf16;
typedef bf16 bf16x4 __attribute__((ext_vector_type(4)));
typedef bf16 bf16x8 __attribute__((ext_vector_type(8)));
typedef float f32x4 __attribute__((ext_vector_type(4)));

// C = tril(A @ B), A/B lower triangular fp32. bf16 MFMA, fp32 accumulate.
// Block = 128x128 C-tile, 256 threads (4 waves, 2x2 of 64x64 per wave).
// K-step = 32 (one mfma_f32_16x16x32_bf16 per 16x16 tile per step).
__global__ __launch_bounds__(256) void tril_mm_kernel(const float* __restrict__ A,
                                                      const float* __restrict__ B,
                                                      float* __restrict__ C) {
    const int bj = blockIdx.x;                    // col block
    const int bi = (NB - 1) - blockIdx.y;         // row block; bottom rows (longest K) dispatch first
    if (bj > bi) return;                          // upper triangle: zeros via memset

    // LDS layout: 16-byte chunks. As chunk(kg, m) = kg*128 + (m ^ (kg<<2)), holds A[m][kg*8..+8]
    //             Bs chunk(kg, n) = kg*128 + (n ^ ((n>>2)&7)), holds B[kg*8..+8][n] (k-contiguous)
    __shared__ __align__(16) bf16 As[4 * 128 * 8];
    __shared__ __align__(16) bf16 Bs[4 * 128 * 8];

    const int tid = threadIdx.x;
    const int wave = tid >> 6;
    const int lane = tid & 63;
    const int wm = (wave >> 1) * 64;   // wave's 64x64 quadrant
    const int wn = (wave & 1) * 64;
    const int l15 = lane & 15;
    const int quad = lane >> 4;        // 0..3

    const int row0 = bi * 128;
    const int col0 = bj * 128;

    // B staging mapping: thread -> (kb, n4); loads a 4x4 fp32 block, transposes in-reg
    const int kb = tid >> 5;           // 0..7  (k rows kb*4 .. kb*4+3)
    const int n4 = tid & 31;           // 0..31 (cols n4*4 .. n4*4+3)

    f32x4 acc[4][4] = {};

    // k range [col0, row0+128): outside it either A[row][k]==0 (k>row) or B[k][col]==0 (k<col)
    for (int k0 = col0; k0 < row0 + 128; k0 += 32) {
        // ---- stage A tile: 128 rows x 32 k, fp32 -> bf16 ----
#pragma unroll
        for (int it = 0; it < 4; ++it) {
            const int c = tid + it * 256;        // 0..1023 float4-chunks
            const int row = c >> 3;
            const int k4 = c & 7;
            f32x4 v = *(const f32x4*)&A[(size_t)(row0 + row) * N + (k0 + k4 * 4)];
            bf16x4 h = { (bf16)v[0], (bf16)v[1], (bf16)v[2], (bf16)v[3] };
            const int kg = k4 >> 1;
            const int jo = (k4 & 1) * 4;
            const int chunk = kg * 128 + (row ^ (kg << 2));
            *(bf16x4*)&As[chunk * 8 + jo] = h;
        }
        // ---- stage B tile: 32 k-rows x 128 cols, transposed into [n][k] ----
        {
            const float* bp = &B[(size_t)(k0 + kb * 4) * N + (col0 + n4 * 4)];
            f32x4 r0 = *(const f32x4*)(bp + 0 * N);
            f32x4 r1 = *(const f32x4*)(bp + 1 * N);
            f32x4 r2 = *(const f32x4*)(bp + 2 * N);
            f32x4 r3 = *(const f32x4*)(bp + 3 * N);
            const int kg = kb >> 1;
            const int jo = (kb & 1) * 4;
#pragma unroll
            for (int i = 0; i < 4; ++i) {
                bf16x4 h = { (bf16)r0[i], (bf16)r1[i], (bf16)r2[i], (bf16)r3[i] };
                const int n = n4 * 4 + i;
                const int nsw = n ^ ((n >> 2) & 7);
                *(bf16x4*)&Bs[(kg * 128 + nsw) * 8 + jo] = h;
            }
        }
        __syncthreads();

        // ---- fragments + MFMA ----
        bf16x8 af[4], bfr[4];
#pragma unroll
        for (int i = 0; i < 4; ++i) {
            const int m = wm + i * 16 + l15;
            af[i] = *(const bf16x8*)&As[(quad * 128 + (m ^ (quad << 2))) * 8];
        }
#pragma unroll
        for (int j = 0; j < 4; ++j) {
            const int n = wn + j * 16 + l15;
            const int nsw = n ^ ((n >> 2) & 7);
            bfr[j] = *(const bf16x8*)&Bs[(quad * 128 + nsw) * 8];
        }
#pragma unroll
        for (int i = 0; i < 4; ++i)
#pragma unroll
            for (int j = 0; j < 4; ++j)
                acc[i][j] = __builtin_amdgcn_mfma_f32_16x16x32_bf16(af[i], bfr[j], acc[i][j], 0, 0, 0);
        __syncthreads();
    }

    // ---- epilogue: C/D layout col = lane&15, row = quad*4 + v ----
    const bool diag = (bi == bj);
#pragma unroll
    for (int i = 0; i < 4; ++i) {
#pragma unroll
        for (int j = 0; j < 4; ++j) {
            const int colg = col0 + wn + j * 16 + l15;
#pragma unroll
            for (int v = 0; v < 4; ++v) {
                const int rowg = row0 + wm + i * 16 + quad * 4 + v;
                if (!diag || colg <= rowg)
                    C[(size_t)rowg * N + colg] = acc[i][j][v];
            }
        }
    }
}

extern "C" void kernel_launch(void* const* d_in, const int* in_sizes, int n_in,
                              void* d_out, int out_size, void* d_ws, size_t ws_size,
                              hipStream_t stream) {
    const float* A = (const float*)d_in[0];
    const float* B = (const float*)d_in[1];
    float* C = (float*)d_out;

    // Upper triangle must be exactly zero (harness poisons d_out with 0xAA).
    hipMemsetAsync(d_out, 0, (size_t)out_size * sizeof(float), stream);

    dim3 grid(NB, NB);
    dim3 block(256);
    tril_mm_kernel<<<grid, block, 0, stream>>>(A, B, C);
}

// Round 2
// 243.737 us; speedup vs baseline: 1.2019x; 1.2019x over previous
//
#include <hip/hip_runtime.h>

#define N 4096
#define NB 32      // N / 128
#define CH 8       // split-K chunk = CH 128-blocks = 1024 K values (<=32 BK32 iters)

typedef __bf16 bf16;
typedef bf16 bf16x4 __attribute__((ext_vector_type(4)));
typedef bf16 bf16x8 __attribute__((ext_vector_type(8)));
typedef float f32x4 __attribute__((ext_vector_type(4)));

// Zero all of C (4096^2 fp32 = 64 MiB) with wide vector stores.
// hipMemsetAsync measured ~0.5 TB/s (122 us) -- this should run at ~6 TB/s.
__global__ __launch_bounds__(256) void zero_c(float* __restrict__ C) {
    f32x4* p = (f32x4*)C;
    const int base = blockIdx.x * 1024 + threadIdx.x;
#pragma unroll
    for (int it = 0; it < 4; ++it)
        p[base + it * 256] = (f32x4){0.f, 0.f, 0.f, 0.f};
}

// C = tril(A @ B), A/B lower triangular fp32. bf16 MFMA, fp32 accumulate.
// 1D grid of balanced work units: (bi, bj, k-chunk). Diagonals decoded
// longest-chunk-first. Split blocks (d >= CH) accumulate via atomicAdd into
// the zeroed C; short blocks plain-store.
__global__ __launch_bounds__(256) void tril_mm_kernel(const float* __restrict__ A,
                                                      const float* __restrict__ B,
                                                      float* __restrict__ C) {
    // ---- decode unit id -> (d, bj, chunk) ; descending d so long chains start first
    int id = blockIdx.x;
    int d = NB - 1;
    for (; d > 0; --d) {
        const int cnt = (NB - d) * ((d >> 3) + 1);  // (NB-d) blocks x S(d) chunks
        if (id < cnt) break;
        id -= cnt;
    }
    const int S = (d >> 3) + 1;         // ceil((d+1)/CH)
    const int bj = id / S;
    const int cidx = id - bj * S;
    const int bi = bj + d;

    const int row0 = bi * 128;
    const int col0 = bj * 128;
    const int kb_start = bj + cidx * CH;
    const int kb_end   = min(kb_start + CH, bi + 1);

    __shared__ __align__(16) bf16 As[4 * 128 * 8];
    __shared__ __align__(16) bf16 Bs[4 * 128 * 8];

    const int tid = threadIdx.x;
    const int wave = tid >> 6;
    const int lane = tid & 63;
    const int wm = (wave >> 1) * 64;
    const int wn = (wave & 1) * 64;
    const int l15 = lane & 15;
    const int quad = lane >> 4;

    const int kb4 = tid >> 5;           // B staging: k rows kb4*4..+3
    const int n4 = tid & 31;            // cols n4*4..+3

    f32x4 acc[4][4] = {};

    for (int k0 = kb_start * 128; k0 < kb_end * 128; k0 += 32) {
        // ---- stage A tile: 128 rows x 32 k, fp32 -> bf16 ----
#pragma unroll
        for (int it = 0; it < 4; ++it) {
            const int c = tid + it * 256;
            const int row = c >> 3;
            const int k4 = c & 7;
            f32x4 v = *(const f32x4*)&A[(size_t)(row0 + row) * N + (k0 + k4 * 4)];
            bf16x4 h = { (bf16)v[0], (bf16)v[1], (bf16)v[2], (bf16)v[3] };
            const int kg = k4 >> 1;
            const int jo = (k4 & 1) * 4;
            const int chunk = kg * 128 + (row ^ (kg << 2));
            *(bf16x4*)&As[chunk * 8 + jo] = h;
        }
        // ---- stage B tile transposed into [n][k] ----
        {
            const float* bp = &B[(size_t)(k0 + kb4 * 4) * N + (col0 + n4 * 4)];
            f32x4 r0 = *(const f32x4*)(bp + 0 * N);
            f32x4 r1 = *(const f32x4*)(bp + 1 * N);
            f32x4 r2 = *(const f32x4*)(bp + 2 * N);
            f32x4 r3 = *(const f32x4*)(bp + 3 * N);
            const int kg = kb4 >> 1;
            const int jo = (kb4 & 1) * 4;
#pragma unroll
            for (int i = 0; i < 4; ++i) {
                bf16x4 h = { (bf16)r0[i], (bf16)r1[i], (bf16)r2[i], (bf16)r3[i] };
                const int n = n4 * 4 + i;
                const int nsw = n ^ ((n >> 2) & 7);
                *(bf16x4*)&Bs[(kg * 128 + nsw) * 8 + jo] = h;
            }
        }
        __syncthreads();

        bf16x8 af[4], bfr[4];
#pragma unroll
        for (int i = 0; i < 4; ++i) {
            const int m = wm + i * 16 + l15;
            af[i] = *(const bf16x8*)&As[(quad * 128 + (m ^ (quad << 2))) * 8];
        }
#pragma unroll
        for (int j = 0; j < 4; ++j) {
            const int n = wn + j * 16 + l15;
            const int nsw = n ^ ((n >> 2) & 7);
            bfr[j] = *(const bf16x8*)&Bs[(quad * 128 + nsw) * 8];
        }
#pragma unroll
        for (int i = 0; i < 4; ++i)
#pragma unroll
            for (int j = 0; j < 4; ++j)
                acc[i][j] = __builtin_amdgcn_mfma_f32_16x16x32_bf16(af[i], bfr[j], acc[i][j], 0, 0, 0);
        __syncthreads();
    }

    // ---- epilogue: C/D layout col = lane&15, row = quad*4 + v ----
    if (S == 1) {
        if (d == 0) {
            // diagonal block: predicated store (upper part stays zero)
#pragma unroll
            for (int i = 0; i < 4; ++i)
#pragma unroll
                for (int j = 0; j < 4; ++j) {
                    const int colg = col0 + wn + j * 16 + l15;
#pragma unroll
                    for (int v = 0; v < 4; ++v) {
                        const int rowg = row0 + wm + i * 16 + quad * 4 + v;
                        if (colg <= rowg) C[(size_t)rowg * N + colg] = acc[i][j][v];
                    }
                }
        } else {
#pragma unroll
            for (int i = 0; i < 4; ++i)
#pragma unroll
                for (int j = 0; j < 4; ++j) {
                    const int colg = col0 + wn + j * 16 + l15;
#pragma unroll
                    for (int v = 0; v < 4; ++v) {
                        const int rowg = row0 + wm + i * 16 + quad * 4 + v;
                        C[(size_t)rowg * N + colg] = acc[i][j][v];
                    }
                }
        }
    } else {
        // split block: accumulate into zero-initialized C
#pragma unroll
        for (int i = 0; i < 4; ++i)
#pragma unroll
            for (int j = 0; j < 4; ++j) {
                const int colg = col0 + wn + j * 16 + l15;
#pragma unroll
                for (int v = 0; v < 4; ++v) {
                    const int rowg = row0 + wm + i * 16 + quad * 4 + v;
                    atomicAdd(&C[(size_t)rowg * N + colg], acc[i][j][v]);
                }
            }
    }
}

extern "C" void kernel_launch(void* const* d_in, const int* in_sizes, int n_in,
                              void* d_out, int out_size, void* d_ws, size_t ws_size,
                              hipStream_t stream) {
    const float* A = (const float*)d_in[0];
    const float* B = (const float*)d_in[1];
    float* C = (float*)d_out;

    // total work units: sum over d of (NB-d) * ceil((d+1)/CH)
    int units = 0;
    for (int d = 0; d < NB; ++d) units += (NB - d) * ((d >> 3) + 1);  // = 1000

    zero_c<<<dim3(4096), dim3(256), 0, stream>>>(C);
    tril_mm_kernel<<<dim3(units), dim3(256), 0, stream>>>(A, B, C);
}

// Round 3
// 243.603 us; speedup vs baseline: 1.2026x; 1.0006x over previous
//
#include <hip/hip_runtime.h>

#define N 4096
#define NB 32      // N / 128
#define CH 8       // split-K chunk = CH 128-blocks (<=32 BK32 iters per unit)

typedef __bf16 bf16;
typedef bf16 bf16x4 __attribute__((ext_vector_type(4)));
typedef bf16 bf16x8 __attribute__((ext_vector_type(8)));
typedef float f32x4 __attribute__((ext_vector_type(4)));

__device__ __forceinline__ int tri(int i) { return (i * (i + 1)) >> 1; }

// async global(16B) -> LDS, wave-uniform LDS base + lane*16
__device__ __forceinline__ void async16(const bf16* g, const bf16* l) {
    __builtin_amdgcn_global_load_lds(
        (const __attribute__((address_space(1))) unsigned int*)g,
        (__attribute__((address_space(3))) unsigned int*)l, 16, 0, 0);
}

// ---- prepass 1: A (fp32, row-major) -> block-compacted bf16 tiles ----
// slot(bi,bk) = tri(bi)+bk, 128x128 bf16 row-major [m][k], only bk <= bi.
__global__ __launch_bounds__(256) void conv_a(const float* __restrict__ A,
                                              bf16* __restrict__ Abf) {
    const int bk = blockIdx.x, bi = blockIdx.y;
    if (bk > bi) return;
    bf16* slot = Abf + (size_t)(tri(bi) + bk) * 16384;
    const int tid = threadIdx.x;
#pragma unroll
    for (int it = 0; it < 8; ++it) {
        const int c = it * 256 + tid;          // 2048 8-elem chunks
        const int row = c >> 4, col8 = c & 15;
        const float* src = &A[(size_t)(bi * 128 + row) * N + bk * 128 + col8 * 8];
        f32x4 v0 = *(const f32x4*)src;
        f32x4 v1 = *(const f32x4*)(src + 4);
        bf16x8 h = { (bf16)v0[0], (bf16)v0[1], (bf16)v0[2], (bf16)v0[3],
                     (bf16)v1[0], (bf16)v1[1], (bf16)v1[2], (bf16)v1[3] };
        *(bf16x8*)&slot[row * 128 + col8 * 8] = h;
    }
}

// ---- prepass 2: B (fp32) -> block-compacted bf16 TRANSPOSED tiles ----
// slot(bn,bk) = tri(bk)+bn (bk >= bn), 128x128 bf16 [n][k]: Bt[n][k]=B[k][n].
__global__ __launch_bounds__(256) void conv_bt(const float* __restrict__ B,
                                               bf16* __restrict__ Btf) {
    const int bk = blockIdx.x, bn = blockIdx.y;
    if (bk < bn) return;
    bf16* slot = Btf + (size_t)(tri(bk) + bn) * 16384;
    const int tid = threadIdx.x;
    const int kq = tid >> 5;                   // k sub-row group (x4)
    const int n4 = tid & 31;                   // n group (x4)
#pragma unroll
    for (int it = 0; it < 4; ++it) {
        const int kl = it * 32 + kq * 4;
        const float* src = &B[(size_t)(bk * 128 + kl) * N + bn * 128 + n4 * 4];
        f32x4 r0 = *(const f32x4*)(src + 0 * N);
        f32x4 r1 = *(const f32x4*)(src + 1 * N);
        f32x4 r2 = *(const f32x4*)(src + 2 * N);
        f32x4 r3 = *(const f32x4*)(src + 3 * N);
#pragma unroll
        for (int i = 0; i < 4; ++i) {
            bf16x4 h = { (bf16)r0[i], (bf16)r1[i], (bf16)r2[i], (bf16)r3[i] };
            *(bf16x4*)&slot[(n4 * 4 + i) * 128 + kl] = h;
        }
    }
}

// ---- zero C (needed for upper triangle + split-K atomic accumulation) ----
__global__ __launch_bounds__(256) void zero_c(float* __restrict__ C) {
    f32x4* p = (f32x4*)C;
    const int base = blockIdx.x * 1024 + threadIdx.x;
#pragma unroll
    for (int it = 0; it < 4; ++it)
        p[base + it * 256] = (f32x4){0.f, 0.f, 0.f, 0.f};
}

// ---- main: m97-style K-loop on bf16 compacted tiles ----
__global__ __launch_bounds__(256) void tril_mm_kernel(const bf16* __restrict__ Abf,
                                                      const bf16* __restrict__ Btf,
                                                      float* __restrict__ C) {
    // decode unit id -> (d, bj, chunk); descending d so long chains start first
    int id = blockIdx.x;
    int d = NB - 1;
    for (; d > 0; --d) {
        const int cnt = (NB - d) * ((d >> 3) + 1);
        if (id < cnt) break;
        id -= cnt;
    }
    const int S = (d >> 3) + 1;
    const int bj = id / S;
    const int cidx = id - bj * S;
    const int bi = bj + d;

    const int kb_start = bj + cidx * CH;
    const int kb_end   = min(kb_start + CH, bi + 1);
    const int triBi = tri(bi);

    __shared__ __align__(16) bf16 As[128 * 32];   // [m][k] row-major, 8 KB
    __shared__ __align__(16) bf16 Bs[128 * 32];   // [n][k] row-major, 8 KB

    const int tid = threadIdx.x;
    const int wave = tid >> 6;
    const int lane = tid & 63;
    const int wm = (wave >> 1) * 64;
    const int wn = (wave & 1) * 64;
    const int l15 = lane & 15;
    const int quad = lane >> 4;
    const int wbase = tid & ~63;                  // wave's first chunk slot

    f32x4 acc[4][4] = {};

    for (int kb = kb_start; kb < kb_end; ++kb) {
        const bf16* Ab = Abf + (size_t)(triBi + kb) * 16384;
        const bf16* Bb = Btf + (size_t)(tri(kb) + bj) * 16384;
#pragma unroll
        for (int kk = 0; kk < 128; kk += 32) {
            // stage A,Bt tiles: 128 rows x 32 k each, 16B per lane per issue
#pragma unroll
            for (int t = 0; t < 2; ++t) {
                const int c = t * 256 + tid;              // chunk: row=c>>2, kg=c&3
                const int goff = (c >> 2) * 128 + kk + (c & 3) * 8;
                const bf16* lbase = (const bf16*)&As[(t * 256 + wbase) * 8];
                async16(Ab + goff, lbase);
                const bf16* lbaseB = (const bf16*)&Bs[(t * 256 + wbase) * 8];
                async16(Bb + goff, lbaseB);
            }
            __syncthreads();

            bf16x8 af[4], bfr[4];
#pragma unroll
            for (int i = 0; i < 4; ++i)
                af[i] = *(const bf16x8*)&As[(wm + i * 16 + l15) * 32 + quad * 8];
#pragma unroll
            for (int j = 0; j < 4; ++j)
                bfr[j] = *(const bf16x8*)&Bs[(wn + j * 16 + l15) * 32 + quad * 8];
#pragma unroll
            for (int i = 0; i < 4; ++i)
#pragma unroll
                for (int j = 0; j < 4; ++j)
                    acc[i][j] = __builtin_amdgcn_mfma_f32_16x16x32_bf16(af[i], bfr[j], acc[i][j], 0, 0, 0);
            __syncthreads();
        }
    }

    // ---- epilogue: C/D layout col = lane&15, row = quad*4 + v ----
    const int row0 = bi * 128, col0 = bj * 128;
    if (S == 1) {
        if (d == 0) {
#pragma unroll
            for (int i = 0; i < 4; ++i)
#pragma unroll
                for (int j = 0; j < 4; ++j) {
                    const int colg = col0 + wn + j * 16 + l15;
#pragma unroll
                    for (int v = 0; v < 4; ++v) {
                        const int rowg = row0 + wm + i * 16 + quad * 4 + v;
                        if (colg <= rowg) C[(size_t)rowg * N + colg] = acc[i][j][v];
                    }
                }
        } else {
#pragma unroll
            for (int i = 0; i < 4; ++i)
#pragma unroll
                for (int j = 0; j < 4; ++j) {
                    const int colg = col0 + wn + j * 16 + l15;
#pragma unroll
                    for (int v = 0; v < 4; ++v) {
                        const int rowg = row0 + wm + i * 16 + quad * 4 + v;
                        C[(size_t)rowg * N + colg] = acc[i][j][v];
                    }
                }
        }
    } else {
#pragma unroll
        for (int i = 0; i < 4; ++i)
#pragma unroll
            for (int j = 0; j < 4; ++j) {
                const int colg = col0 + wn + j * 16 + l15;
#pragma unroll
                for (int v = 0; v < 4; ++v) {
                    const int rowg = row0 + wm + i * 16 + quad * 4 + v;
                    atomicAdd(&C[(size_t)rowg * N + colg], acc[i][j][v]);
                }
            }
    }
}

extern "C" void kernel_launch(void* const* d_in, const int* in_sizes, int n_in,
                              void* d_out, int out_size, void* d_ws, size_t ws_size,
                              hipStream_t stream) {
    const float* A = (const float*)d_in[0];
    const float* B = (const float*)d_in[1];
    float* C = (float*)d_out;
    bf16* Abf = (bf16*)d_ws;                       // 528 tiles x 32 KB = 16.5 MiB
    bf16* Btf = Abf + (size_t)528 * 16384;         // another 16.5 MiB

    int units = 0;
    for (int d = 0; d < NB; ++d) units += (NB - d) * ((d >> 3) + 1);  // = 1000

    conv_a <<<dim3(NB, NB), dim3(256), 0, stream>>>(A, Abf);
    conv_bt<<<dim3(NB, NB), dim3(256), 0, stream>>>(B, Btf);
    zero_c <<<dim3(4096),   dim3(256), 0, stream>>>(C);
    tril_mm_kernel<<<dim3(units), dim3(256), 0, stream>>>(Abf, Btf, C);
}

// Round 4
// 238.055 us; speedup vs baseline: 1.2306x; 1.0233x over previous
//
#include <hip/hip_runtime.h>

#define N 4096
#define NB 32      // N / 128
#define CH 8       // split-K chunk = CH 128-blocks (<=16 BK64 stages per unit)

typedef __bf16 bf16;
typedef bf16 bf16x4 __attribute__((ext_vector_type(4)));
typedef bf16 bf16x8 __attribute__((ext_vector_type(8)));
typedef float f32x4 __attribute__((ext_vector_type(4)));

__device__ __forceinline__ int tri(int i) { return (i * (i + 1)) >> 1; }

// async global(16B) -> LDS, wave-uniform LDS base + lane*16
__device__ __forceinline__ void async16(const bf16* g, const bf16* l) {
    __builtin_amdgcn_global_load_lds(
        (const __attribute__((address_space(1))) unsigned int*)g,
        (__attribute__((address_space(3))) unsigned int*)l, 16, 0, 0);
}

// ---- prepass 1: A (fp32, row-major) -> block-compacted bf16 tiles ----
// slot(bi,bk) = tri(bi)+bk, 128x128 bf16 row-major [m][k], only bk <= bi.
__global__ __launch_bounds__(256) void conv_a(const float* __restrict__ A,
                                              bf16* __restrict__ Abf) {
    const int bk = blockIdx.x, bi = blockIdx.y;
    if (bk > bi) return;
    bf16* slot = Abf + (size_t)(tri(bi) + bk) * 16384;
    const int tid = threadIdx.x;
#pragma unroll
    for (int it = 0; it < 8; ++it) {
        const int c = it * 256 + tid;
        const int row = c >> 4, col8 = c & 15;
        const float* src = &A[(size_t)(bi * 128 + row) * N + bk * 128 + col8 * 8];
        f32x4 v0 = *(const f32x4*)src;
        f32x4 v1 = *(const f32x4*)(src + 4);
        bf16x8 h = { (bf16)v0[0], (bf16)v0[1], (bf16)v0[2], (bf16)v0[3],
                     (bf16)v1[0], (bf16)v1[1], (bf16)v1[2], (bf16)v1[3] };
        *(bf16x8*)&slot[row * 128 + col8 * 8] = h;
    }
}

// ---- prepass 2: B (fp32) -> block-compacted bf16 TRANSPOSED tiles ----
// slot(bn,bk) = tri(bk)+bn (bk >= bn), 128x128 bf16 [n][k]: Bt[n][k]=B[k][n].
__global__ __launch_bounds__(256) void conv_bt(const float* __restrict__ B,
                                               bf16* __restrict__ Btf) {
    const int bk = blockIdx.x, bn = blockIdx.y;
    if (bk < bn) return;
    bf16* slot = Btf + (size_t)(tri(bk) + bn) * 16384;
    const int tid = threadIdx.x;
    const int kq = tid >> 5;
    const int n4 = tid & 31;
#pragma unroll
    for (int it = 0; it < 4; ++it) {
        const int kl = it * 32 + kq * 4;
        const float* src = &B[(size_t)(bk * 128 + kl) * N + bn * 128 + n4 * 4];
        f32x4 r0 = *(const f32x4*)(src + 0 * N);
        f32x4 r1 = *(const f32x4*)(src + 1 * N);
        f32x4 r2 = *(const f32x4*)(src + 2 * N);
        f32x4 r3 = *(const f32x4*)(src + 3 * N);
#pragma unroll
        for (int i = 0; i < 4; ++i) {
            bf16x4 h = { (bf16)r0[i], (bf16)r1[i], (bf16)r2[i], (bf16)r3[i] };
            *(bf16x4*)&slot[(n4 * 4 + i) * 128 + kl] = h;
        }
    }
}

// ---- zero C (upper triangle stays zero; split-K tiles accumulate atomically) ----
__global__ __launch_bounds__(256) void zero_c(float* __restrict__ C) {
    f32x4* p = (f32x4*)C;
    const int base = blockIdx.x * 1024 + threadIdx.x;
#pragma unroll
    for (int it = 0; it < 4; ++it)
        p[base + it * 256] = (f32x4){0.f, 0.f, 0.f, 0.f};
}

// ---- main: BK=64 K-loop, swizzled LDS (conflict-free ds_read_b128) ----
// LDS layout: 16B chunk (row, kg) stored at chunk index row*8 + (kg ^ (row&7)).
// Staging inverts the swizzle in the per-lane GLOBAL address (LDS dest is
// forced to base + lane*16 by global_load_lds).
__global__ __launch_bounds__(256) void tril_mm_kernel(const bf16* __restrict__ Abf,
                                                      const bf16* __restrict__ Btf,
                                                      float* __restrict__ C) {
    // decode unit id -> (d, bj, chunk); descending d so long chains start first
    int id = blockIdx.x;
    int d = NB - 1;
    for (; d > 0; --d) {
        const int cnt = (NB - d) * ((d >> 3) + 1);
        if (id < cnt) break;
        id -= cnt;
    }
    const int S = (d >> 3) + 1;
    const int bj = id / S;
    const int cidx = id - bj * S;
    const int bi = bj + d;

    const int kb_start = bj + cidx * CH;
    const int kb_end   = min(kb_start + CH, bi + 1);
    const int triBi = tri(bi);

    __shared__ __align__(16) bf16 As[128 * 64];   // 16 KB, swizzled chunks
    __shared__ __align__(16) bf16 Bs[128 * 64];   // 16 KB

    const int tid = threadIdx.x;
    const int wave = tid >> 6;
    const int wm = (wave >> 1) * 64;
    const int wn = (wave & 1) * 64;
    const int l15 = tid & 15;
    const int quad = (tid & 63) >> 4;
    const int wbase = tid & ~63;

    // per-lane global chunk offsets for staging (loop-invariant, +kk each stage)
    int goff[4];
#pragma unroll
    for (int t = 0; t < 4; ++t) {
        const int s = t * 256 + tid;          // LDS chunk this lane's data lands in
        const int row = s >> 3;
        const int kg = (s & 7) ^ (row & 7);   // inverse swizzle
        goff[t] = row * 128 + kg * 8;
    }
    // fragment LDS chunk indices (loop-invariant)
    int ach[4][2], bch[4][2];
#pragma unroll
    for (int i = 0; i < 4; ++i)
#pragma unroll
        for (int h = 0; h < 2; ++h) {
            const int m = wm + i * 16 + l15;
            const int n = wn + i * 16 + l15;
            const int kg = h * 4 + quad;
            ach[i][h] = m * 8 + (kg ^ (m & 7));
            bch[i][h] = n * 8 + (kg ^ (n & 7));
        }

    f32x4 acc[4][4] = {};

    for (int kb = kb_start; kb < kb_end; ++kb) {
        const bf16* Ab = Abf + (size_t)(triBi + kb) * 16384;
        const bf16* Bb = Btf + (size_t)(tri(kb) + bj) * 16384;
#pragma unroll
        for (int kk = 0; kk < 128; kk += 64) {
#pragma unroll
            for (int t = 0; t < 4; ++t) {
                async16(Ab + kk + goff[t], &As[(t * 256 + wbase) * 8]);
                async16(Bb + kk + goff[t], &Bs[(t * 256 + wbase) * 8]);
            }
            __syncthreads();
#pragma unroll
            for (int h = 0; h < 2; ++h) {
                bf16x8 af[4], bfr[4];
#pragma unroll
                for (int i = 0; i < 4; ++i) {
                    af[i]  = *(const bf16x8*)&As[ach[i][h] * 8];
                    bfr[i] = *(const bf16x8*)&Bs[bch[i][h] * 8];
                }
#pragma unroll
                for (int i = 0; i < 4; ++i)
#pragma unroll
                    for (int j = 0; j < 4; ++j)
                        acc[i][j] = __builtin_amdgcn_mfma_f32_16x16x32_bf16(af[i], bfr[j], acc[i][j], 0, 0, 0);
            }
            __syncthreads();
        }
    }

    // ---- epilogue: C/D layout col = lane&15, row = quad*4 + v ----
    // Diagonal tiles store unpredicated: A,B exactly triangular => upper accs
    // are exact +0, matching the required zeros.
    const int row0 = bi * 128, col0 = bj * 128;
    if (S == 1) {
#pragma unroll
        for (int i = 0; i < 4; ++i)
#pragma unroll
            for (int j = 0; j < 4; ++j) {
                const int colg = col0 + wn + j * 16 + l15;
#pragma unroll
                for (int v = 0; v < 4; ++v) {
                    const int rowg = row0 + wm + i * 16 + quad * 4 + v;
                    C[(size_t)rowg * N + colg] = acc[i][j][v];
                }
            }
    } else {
#pragma unroll
        for (int i = 0; i < 4; ++i)
#pragma unroll
            for (int j = 0; j < 4; ++j) {
                const int colg = col0 + wn + j * 16 + l15;
#pragma unroll
                for (int v = 0; v < 4; ++v) {
                    const int rowg = row0 + wm + i * 16 + quad * 4 + v;
                    atomicAdd(&C[(size_t)rowg * N + colg], acc[i][j][v]);
                }
            }
    }
}

extern "C" void kernel_launch(void* const* d_in, const int* in_sizes, int n_in,
                              void* d_out, int out_size, void* d_ws, size_t ws_size,
                              hipStream_t stream) {
    const float* A = (const float*)d_in[0];
    const float* B = (const float*)d_in[1];
    float* C = (float*)d_out;
    bf16* Abf = (bf16*)d_ws;                       // 528 tiles x 32 KB = 16.5 MiB
    bf16* Btf = Abf + (size_t)528 * 16384;         // another 16.5 MiB

    int units = 0;
    for (int d = 0; d < NB; ++d) units += (NB - d) * ((d >> 3) + 1);  // = 1000

    conv_a <<<dim3(NB, NB), dim3(256), 0, stream>>>(A, Abf);
    conv_bt<<<dim3(NB, NB), dim3(256), 0, stream>>>(B, Btf);
    zero_c <<<dim3(4096),   dim3(256), 0, stream>>>(C);
    tril_mm_kernel<<<dim3(units), dim3(256), 0, stream>>>(Abf, Btf, C);
}